// Round 9
// baseline (307.419 us; speedup 1.0000x reference)
//
#include <hip/hip_runtime.h>
#include <hip/hip_fp16.h>

// Ontomap: loss = sum((n2f@n_e - f_e)^2) + sum((m2f@m_e - f_e)^2)
// B = 1,048,576, D = 64.
// Round 9: all tables fp8-e4m3 (64 B rows). Two changes vs R8, both targeting
// the random-line-request concurrency limit:
//  (1) K-REMAP: k = hi*32 + t*8 + j, so each lane's A-fragment is 32
//      contiguous bytes -> 2 dwordx4 loads per row (6 gather insts/iter,
//      half of R8's 12; per-row line-requests 4 -> 2). B and -I fragments
//      packed with the same permutation (we build them from fp32 ourselves).
//  (2) SOFTWARE PIPELINE: fragments prefetched one iteration ahead, indices
//      two ahead -> ~6 gather insts in flight DURING compute instead of a
//      full drain before each compute phase.

typedef _Float16 half8 __attribute__((ext_vector_type(8)));
typedef __fp16  fp16x2 __attribute__((ext_vector_type(2)));
typedef float floatx16 __attribute__((ext_vector_type(16)));

#define NBLOCKS 1024
#define SPB 128                 // samples per block: 4 waves * 32
#define NCI_ELEMS 9600000       // 150000 * 64
#define FMA_ELEMS 6400000       // 100000 * 64

__device__ inline half8 cvt8(float4 a, float4 b) {
    union { half8 h; fp16x2 h2[4]; } u;
    u.h2[0] = __builtin_amdgcn_cvt_pkrtz(a.x, a.y);
    u.h2[1] = __builtin_amdgcn_cvt_pkrtz(a.z, a.w);
    u.h2[2] = __builtin_amdgcn_cvt_pkrtz(b.x, b.y);
    u.h2[3] = __builtin_amdgcn_cvt_pkrtz(b.z, b.w);
    return u.h;
}

__device__ inline uint2 pack4(float4 v) {
    union { fp16x2 h2[2]; uint2 u; } p;
    p.h2[0] = __builtin_amdgcn_cvt_pkrtz(v.x, v.y);
    p.h2[1] = __builtin_amdgcn_cvt_pkrtz(v.z, v.w);
    return p.u;
}

// 8 fp32 -> 8 fp8-e4m3 bytes (ascending order).
__device__ inline uint2 pack8_fp8(float4 a, float4 b) {
    int lo = 0, hi = 0;
    lo = __builtin_amdgcn_cvt_pk_fp8_f32(a.x, a.y, lo, false);
    lo = __builtin_amdgcn_cvt_pk_fp8_f32(a.z, a.w, lo, true);
    hi = __builtin_amdgcn_cvt_pk_fp8_f32(b.x, b.y, hi, false);
    hi = __builtin_amdgcn_cvt_pk_fp8_f32(b.z, b.w, hi, true);
    uint2 r; r.x = (unsigned)lo; r.y = (unsigned)hi; return r;
}

__device__ inline long pack8_fp8_l(const float* p) {
    uint2 b = pack8_fp8(*(const float4*)p, *(const float4*)(p + 4));
    return (long)(((unsigned long)b.y << 32) | b.x);
}

// ---- streaming conversion: both tables -> fp8, into workspace.
__global__ __launch_bounds__(256) void convert_kernel(
    const float4* __restrict__ nci, const float4* __restrict__ fma,
    uint2* __restrict__ nci8, uint2* __restrict__ fma8)
{
    const int stride = gridDim.x * blockDim.x;
    const int tid = blockIdx.x * blockDim.x + threadIdx.x;
    for (int i = tid; i < NCI_ELEMS / 8; i += stride)
        nci8[i] = pack8_fp8(nci[2 * i], nci[2 * i + 1]);
    for (int i = tid; i < FMA_ELEMS / 8; i += stride)
        fma8[i] = pack8_fp8(fma[2 * i], fma[2 * i + 1]);
}

// One iteration's gathered fragments: 3 tables x 32 contiguous bytes/lane.
struct FragSet { ulonglong2 n0, n1, m0, m1, f0, f1; };

__device__ inline FragSet gather_frags(
    const unsigned char* __restrict__ nci8, const unsigned char* __restrict__ fma8,
    int in0, int im0, int if0, int hoff)
{
    FragSet s;
    const unsigned char* pn = nci8 + (long)in0 * 64 + hoff;
    const unsigned char* pm = nci8 + (long)im0 * 64 + hoff;
    const unsigned char* pf = fma8 + (long)if0 * 64 + hoff;
    s.n0 = *(const ulonglong2*)pn;  s.n1 = *(const ulonglong2*)(pn + 16);
    s.m0 = *(const ulonglong2*)pm;  s.m1 = *(const ulonglong2*)(pm + 16);
    s.f0 = *(const ulonglong2*)pf;  s.f1 = *(const ulonglong2*)(pf + 16);
    return s;
}

__device__ inline void compute_set(
    const FragSet& s, const long Bn[2][4], const long Bm[2][4],
    const long If0[4], const long If1[4], float& loss)
{
    const long An[4] = {(long)s.n0.x, (long)s.n0.y, (long)s.n1.x, (long)s.n1.y};
    const long Am[4] = {(long)s.m0.x, (long)s.m0.y, (long)s.m1.x, (long)s.m1.y};
    const long Ff[4] = {(long)s.f0.x, (long)s.f0.y, (long)s.f1.x, (long)s.f1.y};

    {   // n-loss, tile 0 (dims 0..31)
        floatx16 a{};
#pragma unroll
        for (int t = 0; t < 4; ++t)
            a = __builtin_amdgcn_mfma_f32_32x32x16_fp8_fp8(An[t], Bn[0][t], a, 0, 0, 0);
#pragma unroll
        for (int t = 0; t < 4; ++t)
            a = __builtin_amdgcn_mfma_f32_32x32x16_fp8_fp8(Ff[t], If0[t], a, 0, 0, 0);
#pragma unroll
        for (int r = 0; r < 16; ++r) loss = fmaf(a[r], a[r], loss);
    }
    {   // n-loss, tile 1 (dims 32..63)
        floatx16 a{};
#pragma unroll
        for (int t = 0; t < 4; ++t)
            a = __builtin_amdgcn_mfma_f32_32x32x16_fp8_fp8(An[t], Bn[1][t], a, 0, 0, 0);
#pragma unroll
        for (int t = 0; t < 4; ++t)
            a = __builtin_amdgcn_mfma_f32_32x32x16_fp8_fp8(Ff[t], If1[t], a, 0, 0, 0);
#pragma unroll
        for (int r = 0; r < 16; ++r) loss = fmaf(a[r], a[r], loss);
    }
    {   // m-loss, tile 0
        floatx16 a{};
#pragma unroll
        for (int t = 0; t < 4; ++t)
            a = __builtin_amdgcn_mfma_f32_32x32x16_fp8_fp8(Am[t], Bm[0][t], a, 0, 0, 0);
#pragma unroll
        for (int t = 0; t < 4; ++t)
            a = __builtin_amdgcn_mfma_f32_32x32x16_fp8_fp8(Ff[t], If0[t], a, 0, 0, 0);
#pragma unroll
        for (int r = 0; r < 16; ++r) loss = fmaf(a[r], a[r], loss);
    }
    {   // m-loss, tile 1
        floatx16 a{};
#pragma unroll
        for (int t = 0; t < 4; ++t)
            a = __builtin_amdgcn_mfma_f32_32x32x16_fp8_fp8(Am[t], Bm[1][t], a, 0, 0, 0);
#pragma unroll
        for (int t = 0; t < 4; ++t)
            a = __builtin_amdgcn_mfma_f32_32x32x16_fp8_fp8(Ff[t], If1[t], a, 0, 0, 0);
#pragma unroll
        for (int r = 0; r < 16; ++r) loss = fmaf(a[r], a[r], loss);
    }
}

// ---- main kernel: fp8 everything, K-remap dwordx4 gathers, pipelined.
__global__ __launch_bounds__(256, 3) void ontomap_kernel_q(
    const int* __restrict__ pos_n, const int* __restrict__ pos_m,
    const int* __restrict__ pos_f,
    const unsigned char* __restrict__ nci8, const unsigned char* __restrict__ fma8,
    const float* __restrict__ n2f, const float* __restrict__ m2f,
    float* __restrict__ out, int iters)
{
    const int lane = threadIdx.x & 63;
    const int wave = threadIdx.x >> 6;
    const int l31  = lane & 31;
    const int hi   = lane >> 5;
    const int hoff = hi * 32;     // this lane's contiguous 32-byte half-row

    // B fragments under the K-remap k = hoff + t*8 + j:
    // MFMA step t, B slot (hi,j) = M[n][hoff + t*8 + j], n = nt*32 + l31.
    long Bn[2][4], Bm[2][4];
#pragma unroll
    for (int nt = 0; nt < 2; ++nt) {
#pragma unroll
        for (int t = 0; t < 4; ++t) {
            Bn[nt][t] = pack8_fp8_l(n2f + (nt * 32 + l31) * 64 + hoff + t * 8);
            Bm[nt][t] = pack8_fp8_l(m2f + (nt * 32 + l31) * 64 + hoff + t * 8);
        }
    }

    // -I fragments (fp8 0xB8 = -1.0 e4m3). Under the remap, tile0's
    // diagonal lives in hi=0 slots, tile1's in hi=1 slots, spread over all
    // 4 steps: step t has -1 at byte j = l31 - t*8 (when 0<=j<8).
    long If0[4], If1[4];
#pragma unroll
    for (int t = 0; t < 4; ++t) {
        const unsigned j = (unsigned)(l31 - t * 8);
        const long pat = (j < 8) ? (long)(0xB8ULL << (8 * j)) : 0L;
        If0[t] = hi ? 0L : pat;
        If1[t] = hi ? pat : 0L;
    }

    const int base = blockIdx.x * SPB + wave * 32 + l31;
    const int istep = NBLOCKS * SPB;

    // Pipeline fill: indices for iters 0,1; fragments for 0,1; indices for 2.
    int aN = pos_n[base], aM = pos_m[base], aF = pos_f[base];
    int bN = 0, bM = 0, bF = 0;
    if (1 < iters) { bN = pos_n[istep + base]; bM = pos_m[istep + base]; bF = pos_f[istep + base]; }
    FragSet F0 = gather_frags(nci8, fma8, aN, aM, aF, hoff);
    FragSet F1 = gather_frags(nci8, fma8, bN, bM, bF, hoff);
    int cN = 0, cM = 0, cF = 0;
    if (2 < iters) { int s = 2 * istep + base; cN = pos_n[s]; cM = pos_m[s]; cF = pos_f[s]; }

    float loss = 0.0f;

#pragma unroll 1
    for (int it = 0; it < iters; it += 2) {
        // F0 = data(it), F1 = data(it+1), c* = idx(it+2) ready.
        compute_set(F0, Bn, Bm, If0, If1, loss);
        if (it + 2 < iters) F0 = gather_frags(nci8, fma8, cN, cM, cF, hoff);
        int dN = 0, dM = 0, dF = 0;
        if (it + 3 < iters) { int s = (it + 3) * istep + base; dN = pos_n[s]; dM = pos_m[s]; dF = pos_f[s]; }
        compute_set(F1, Bn, Bm, If0, If1, loss);
        if (it + 3 < iters) F1 = gather_frags(nci8, fma8, dN, dM, dF, hoff);
        if (it + 4 < iters) { int s = (it + 4) * istep + base; cN = pos_n[s]; cM = pos_m[s]; cF = pos_f[s]; }
    }

#pragma unroll
    for (int o = 32; o > 0; o >>= 1) loss += __shfl_xor(loss, o, 64);
    if (lane == 0) atomicAdd(out, loss);
}

// ---- fallback: fp32 tables with LDS staging (round-4 style), if ws too small.
#define ROW_BYTES 144
__global__ __launch_bounds__(256, 2) void ontomap_kernel_f32(
    const int* __restrict__ pos_n, const int* __restrict__ pos_m,
    const int* __restrict__ pos_f,
    const float* __restrict__ nci, const float* __restrict__ fma_emb,
    const float* __restrict__ n2f, const float* __restrict__ m2f,
    float* __restrict__ out, int iters)
{
    __shared__ char lds[4 * 2 * 32 * ROW_BYTES];

    const int lane = threadIdx.x & 63;
    const int wave = threadIdx.x >> 6;
    const int l31  = lane & 31;
    const int hi   = lane >> 5;
    const int kbase = hi * 8;
    const int srow   = lane >> 4;
    const int schunk = lane & 15;

    char* const nbase = lds + wave * (2 * 32 * ROW_BYTES);
    char* const mbase = nbase + 32 * ROW_BYTES;

    half8 Bn[2][4], Bm[2][4];
#pragma unroll
    for (int nt = 0; nt < 2; ++nt) {
#pragma unroll
        for (int t = 0; t < 4; ++t) {
            const float* p = n2f + (nt * 32 + l31) * 64 + t * 16 + kbase;
            Bn[nt][t] = cvt8(*(const float4*)p, *(const float4*)(p + 4));
            const float* q = m2f + (nt * 32 + l31) * 64 + t * 16 + kbase;
            Bm[nt][t] = cvt8(*(const float4*)q, *(const float4*)(q + 4));
        }
    }

    float loss = 0.0f;
    int in_, im_, if_;
    {
        int s = blockIdx.x * SPB + wave * 32 + l31;
        in_ = pos_n[s]; im_ = pos_m[s]; if_ = pos_f[s];
    }

#pragma unroll 1
    for (int it = 0; it < iters; ++it) {
        const int in0 = in_, im0 = im_, if0 = if_;
        if (it + 1 < iters) {
            int s = ((it + 1) * NBLOCKS + blockIdx.x) * SPB + wave * 32 + l31;
            in_ = pos_n[s]; im_ = pos_m[s]; if_ = pos_f[s];
        }

#pragma unroll
        for (int i = 0; i < 8; ++i) {
            const int rl = i * 4 + srow;
            const int rn = __shfl(in0, rl, 64);
            float4 v = ((const float4*)(nci + (long)rn * 64))[schunk];
            *(uint2*)(nbase + rl * ROW_BYTES + schunk * 8) = pack4(v);
            const int rm = __shfl(im0, rl, 64);
            float4 w = ((const float4*)(nci + (long)rm * 64))[schunk];
            *(uint2*)(mbase + rl * ROW_BYTES + schunk * 8) = pack4(w);
        }
        asm volatile("" ::: "memory");

        floatx16 aN0{}, aN1{}, aM0{}, aM1{};
#pragma unroll
        for (int t = 0; t < 4; ++t) {
            half8 aF = *(const half8*)(nbase + l31 * ROW_BYTES + t * 32 + hi * 16);
            aN0 = __builtin_amdgcn_mfma_f32_32x32x16_f16(aF, Bn[0][t], aN0, 0, 0, 0);
            aN1 = __builtin_amdgcn_mfma_f32_32x32x16_f16(aF, Bn[1][t], aN1, 0, 0, 0);
            half8 bF = *(const half8*)(mbase + l31 * ROW_BYTES + t * 32 + hi * 16);
            aM0 = __builtin_amdgcn_mfma_f32_32x32x16_f16(bF, Bm[0][t], aM0, 0, 0, 0);
            aM1 = __builtin_amdgcn_mfma_f32_32x32x16_f16(bF, Bm[1][t], aM1, 0, 0, 0);
        }

#pragma unroll
        for (int r = 0; r < 16; ++r) {
            const int mrow = (r & 3) + 8 * (r >> 2) + 4 * hi;
            const int fid  = __shfl(if0, mrow, 64);
            const float* pf = fma_emb + (long)fid * 64 + l31;
            const float f0 = pf[0];
            const float f1 = pf[32];
            float d;
            d = aN0[r] - f0; loss = fmaf(d, d, loss);
            d = aM0[r] - f0; loss = fmaf(d, d, loss);
            d = aN1[r] - f1; loss = fmaf(d, d, loss);
            d = aM1[r] - f1; loss = fmaf(d, d, loss);
        }
    }

#pragma unroll
    for (int o = 32; o > 0; o >>= 1) loss += __shfl_xor(loss, o, 64);
    if (lane == 0) atomicAdd(out, loss);
}

extern "C" void kernel_launch(void* const* d_in, const int* in_sizes, int n_in,
                              void* d_out, int out_size, void* d_ws, size_t ws_size,
                              hipStream_t stream) {
    const int*   pos_n   = (const int*)d_in[0];
    const int*   pos_m   = (const int*)d_in[1];
    const int*   pos_f   = (const int*)d_in[2];
    const float* nci_emb = (const float*)d_in[3];
    const float* fma_emb = (const float*)d_in[4];
    const float* n2f_mat = (const float*)d_in[5];
    const float* m2f_mat = (const float*)d_in[6];
    float* out = (float*)d_out;

    const int B = in_sizes[0];
    const int iters = B / (NBLOCKS * SPB);  // 1,048,576 -> 8

    (void)hipMemsetAsync(out, 0, sizeof(float), stream);

    const size_t need = (size_t)NCI_ELEMS + (size_t)FMA_ELEMS;  // 16 MB
    if (ws_size >= need) {
        unsigned char* nci8 = (unsigned char*)d_ws;
        unsigned char* fma8 = nci8 + NCI_ELEMS;   // 9,600,000 is 64B-aligned
        convert_kernel<<<2048, 256, 0, stream>>>(
            (const float4*)nci_emb, (const float4*)fma_emb,
            (uint2*)nci8, (uint2*)fma8);
        ontomap_kernel_q<<<NBLOCKS, 256, 0, stream>>>(
            pos_n, pos_m, pos_f, nci8, fma8, n2f_mat, m2f_mat, out, iters);
    } else {
        ontomap_kernel_f32<<<NBLOCKS, 256, 0, stream>>>(
            pos_n, pos_m, pos_f, nci_emb, fma_emb, n2f_mat, m2f_mat, out, iters);
    }
}

// Round 10
// 186.130 us; speedup vs baseline: 1.6516x; 1.6516x over previous
//
#include <hip/hip_runtime.h>
#include <hip/hip_fp16.h>

// Ontomap: loss = sum((n2f@n_e - f_e)^2) + sum((m2f@m_e - f_e)^2)
// B = 1,048,576, D = 64.
// Round 10: R8 skeleton (fp8 tables, register-direct gathers, sequential
// 16-reg accumulator tiles, index-only prefetch) + K-REMAP k = hi*32+t*8+j
// so each lane's A-fragment is 32 contiguous bytes -> 2 dwordx4 loads per
// table = 6 gather insts/iter (R8: 12), line-requests halved. No structs,
// no fragment double-buffer (R9's FragSet pipeline spilled to scratch:
// WRITE_SIZE 289 MB). Load order An,Ff,Am; tiles n0,n1,m0,m1 so Am is in
// flight under the n-tile MFMAs.

typedef _Float16 half8 __attribute__((ext_vector_type(8)));
typedef __fp16  fp16x2 __attribute__((ext_vector_type(2)));
typedef float floatx16 __attribute__((ext_vector_type(16)));

#define NBLOCKS 1024
#define SPB 128                 // samples per block: 4 waves * 32
#define NCI_ELEMS 9600000       // 150000 * 64
#define FMA_ELEMS 6400000       // 100000 * 64

__device__ inline half8 cvt8(float4 a, float4 b) {
    union { half8 h; fp16x2 h2[4]; } u;
    u.h2[0] = __builtin_amdgcn_cvt_pkrtz(a.x, a.y);
    u.h2[1] = __builtin_amdgcn_cvt_pkrtz(a.z, a.w);
    u.h2[2] = __builtin_amdgcn_cvt_pkrtz(b.x, b.y);
    u.h2[3] = __builtin_amdgcn_cvt_pkrtz(b.z, b.w);
    return u.h;
}

__device__ inline uint2 pack4(float4 v) {
    union { fp16x2 h2[2]; uint2 u; } p;
    p.h2[0] = __builtin_amdgcn_cvt_pkrtz(v.x, v.y);
    p.h2[1] = __builtin_amdgcn_cvt_pkrtz(v.z, v.w);
    return p.u;
}

// 8 fp32 -> 8 fp8-e4m3 bytes (ascending order).
__device__ inline uint2 pack8_fp8(float4 a, float4 b) {
    int lo = 0, hi = 0;
    lo = __builtin_amdgcn_cvt_pk_fp8_f32(a.x, a.y, lo, false);
    lo = __builtin_amdgcn_cvt_pk_fp8_f32(a.z, a.w, lo, true);
    hi = __builtin_amdgcn_cvt_pk_fp8_f32(b.x, b.y, hi, false);
    hi = __builtin_amdgcn_cvt_pk_fp8_f32(b.z, b.w, hi, true);
    uint2 r; r.x = (unsigned)lo; r.y = (unsigned)hi; return r;
}

__device__ inline long pack8_fp8_l(const float* p) {
    uint2 b = pack8_fp8(*(const float4*)p, *(const float4*)(p + 4));
    return (long)(((unsigned long)b.y << 32) | b.x);
}

// ---- streaming conversion: both tables -> fp8, into workspace.
__global__ __launch_bounds__(256) void convert_kernel(
    const float4* __restrict__ nci, const float4* __restrict__ fma,
    uint2* __restrict__ nci8, uint2* __restrict__ fma8)
{
    const int stride = gridDim.x * blockDim.x;
    const int tid = blockIdx.x * blockDim.x + threadIdx.x;
    for (int i = tid; i < NCI_ELEMS / 8; i += stride)
        nci8[i] = pack8_fp8(nci[2 * i], nci[2 * i + 1]);
    for (int i = tid; i < FMA_ELEMS / 8; i += stride)
        fma8[i] = pack8_fp8(fma[2 * i], fma[2 * i + 1]);
}

// ---- main kernel: fp8 tables, K-remapped dwordx4 gathers, sequential tiles.
__global__ __launch_bounds__(256, 4) void ontomap_kernel_q(
    const int* __restrict__ pos_n, const int* __restrict__ pos_m,
    const int* __restrict__ pos_f,
    const unsigned char* __restrict__ nci8, const unsigned char* __restrict__ fma8,
    const float* __restrict__ n2f, const float* __restrict__ m2f,
    float* __restrict__ out, int iters)
{
    const int lane = threadIdx.x & 63;
    const int wave = threadIdx.x >> 6;
    const int l31  = lane & 31;
    const int hi   = lane >> 5;
    const int hoff = hi * 32;     // this lane's contiguous 32-byte half-row

    // B fragments under the K-remap k = hoff + t*8 + j:
    // MFMA step t, B slot (hi,j) = M[n][hoff + t*8 + j], n = nt*32 + l31.
    long Bn[2][4], Bm[2][4];
#pragma unroll
    for (int nt = 0; nt < 2; ++nt) {
#pragma unroll
        for (int t = 0; t < 4; ++t) {
            Bn[nt][t] = pack8_fp8_l(n2f + (nt * 32 + l31) * 64 + hoff + t * 8);
            Bm[nt][t] = pack8_fp8_l(m2f + (nt * 32 + l31) * 64 + hoff + t * 8);
        }
    }

    // -I fragments (fp8 0xB8 = -1.0 e4m3). Under the remap, tile0's diagonal
    // lives in hi=0 slots, tile1's in hi=1 slots: step t has -1 at byte
    // j = l31 - t*8 when 0 <= j < 8.  (Verified correct in round 9.)
    long If0[4], If1[4];
#pragma unroll
    for (int t = 0; t < 4; ++t) {
        const unsigned j = (unsigned)(l31 - t * 8);
        const long pat = (j < 8) ? (long)(0xB8ULL << (8 * j)) : 0L;
        If0[t] = hi ? 0L : pat;
        If1[t] = hi ? pat : 0L;
    }

    float loss = 0.0f;

    int in_, im_, if_;
    {
        int s = blockIdx.x * SPB + wave * 32 + l31;
        in_ = pos_n[s]; im_ = pos_m[s]; if_ = pos_f[s];
    }

#pragma unroll 1
    for (int it = 0; it < iters; ++it) {
        const int in0 = in_, im0 = im_, if0 = if_;
        if (it + 1 < iters) {
            int s = ((it + 1) * NBLOCKS + blockIdx.x) * SPB + wave * 32 + l31;
            in_ = pos_n[s]; im_ = pos_m[s]; if_ = pos_f[s];
        }

        // ---- 6 independent dwordx4 gathers (32 contiguous B per lane).
        // Order: An, Ff, Am -- so Am is still in flight during n-tiles.
        const unsigned char* pn = nci8 + (long)in0 * 64 + hoff;
        const unsigned char* pf = fma8 + (long)if0 * 64 + hoff;
        const unsigned char* pm = nci8 + (long)im0 * 64 + hoff;

        ulonglong2 n01 = *(const ulonglong2*)pn;
        ulonglong2 n23 = *(const ulonglong2*)(pn + 16);
        ulonglong2 f01 = *(const ulonglong2*)pf;
        ulonglong2 f23 = *(const ulonglong2*)(pf + 16);
        ulonglong2 m01 = *(const ulonglong2*)pm;
        ulonglong2 m23 = *(const ulonglong2*)(pm + 16);

        const long An[4] = {(long)n01.x, (long)n01.y, (long)n23.x, (long)n23.y};
        const long Ff[4] = {(long)f01.x, (long)f01.y, (long)f23.x, (long)f23.y};
        const long Am[4] = {(long)m01.x, (long)m01.y, (long)m23.x, (long)m23.y};

        // ---- sequential tiles: one 16-reg accumulator live at a time.
        {   // n-loss, tile 0 (dims 0..31)
            floatx16 a{};
#pragma unroll
            for (int t = 0; t < 4; ++t)
                a = __builtin_amdgcn_mfma_f32_32x32x16_fp8_fp8(An[t], Bn[0][t], a, 0, 0, 0);
#pragma unroll
            for (int t = 0; t < 4; ++t)
                a = __builtin_amdgcn_mfma_f32_32x32x16_fp8_fp8(Ff[t], If0[t], a, 0, 0, 0);
#pragma unroll
            for (int r = 0; r < 16; ++r) loss = fmaf(a[r], a[r], loss);
        }
        {   // n-loss, tile 1 (dims 32..63)
            floatx16 a{};
#pragma unroll
            for (int t = 0; t < 4; ++t)
                a = __builtin_amdgcn_mfma_f32_32x32x16_fp8_fp8(An[t], Bn[1][t], a, 0, 0, 0);
#pragma unroll
            for (int t = 0; t < 4; ++t)
                a = __builtin_amdgcn_mfma_f32_32x32x16_fp8_fp8(Ff[t], If1[t], a, 0, 0, 0);
#pragma unroll
            for (int r = 0; r < 16; ++r) loss = fmaf(a[r], a[r], loss);
        }
        {   // m-loss, tile 0
            floatx16 a{};
#pragma unroll
            for (int t = 0; t < 4; ++t)
                a = __builtin_amdgcn_mfma_f32_32x32x16_fp8_fp8(Am[t], Bm[0][t], a, 0, 0, 0);
#pragma unroll
            for (int t = 0; t < 4; ++t)
                a = __builtin_amdgcn_mfma_f32_32x32x16_fp8_fp8(Ff[t], If0[t], a, 0, 0, 0);
#pragma unroll
            for (int r = 0; r < 16; ++r) loss = fmaf(a[r], a[r], loss);
        }
        {   // m-loss, tile 1
            floatx16 a{};
#pragma unroll
            for (int t = 0; t < 4; ++t)
                a = __builtin_amdgcn_mfma_f32_32x32x16_fp8_fp8(Am[t], Bm[1][t], a, 0, 0, 0);
#pragma unroll
            for (int t = 0; t < 4; ++t)
                a = __builtin_amdgcn_mfma_f32_32x32x16_fp8_fp8(Ff[t], If1[t], a, 0, 0, 0);
#pragma unroll
            for (int r = 0; r < 16; ++r) loss = fmaf(a[r], a[r], loss);
        }
    }

#pragma unroll
    for (int o = 32; o > 0; o >>= 1) loss += __shfl_xor(loss, o, 64);
    if (lane == 0) atomicAdd(out, loss);
}

// ---- fallback: fp32 tables with LDS staging (round-4 style), if ws too small.
#define ROW_BYTES 144
__global__ __launch_bounds__(256, 2) void ontomap_kernel_f32(
    const int* __restrict__ pos_n, const int* __restrict__ pos_m,
    const int* __restrict__ pos_f,
    const float* __restrict__ nci, const float* __restrict__ fma_emb,
    const float* __restrict__ n2f, const float* __restrict__ m2f,
    float* __restrict__ out, int iters)
{
    __shared__ char lds[4 * 2 * 32 * ROW_BYTES];

    const int lane = threadIdx.x & 63;
    const int wave = threadIdx.x >> 6;
    const int l31  = lane & 31;
    const int hi   = lane >> 5;
    const int kbase = hi * 8;
    const int srow   = lane >> 4;
    const int schunk = lane & 15;

    char* const nbase = lds + wave * (2 * 32 * ROW_BYTES);
    char* const mbase = nbase + 32 * ROW_BYTES;

    half8 Bn[2][4], Bm[2][4];
#pragma unroll
    for (int nt = 0; nt < 2; ++nt) {
#pragma unroll
        for (int t = 0; t < 4; ++t) {
            const float* p = n2f + (nt * 32 + l31) * 64 + t * 16 + kbase;
            Bn[nt][t] = cvt8(*(const float4*)p, *(const float4*)(p + 4));
            const float* q = m2f + (nt * 32 + l31) * 64 + t * 16 + kbase;
            Bm[nt][t] = cvt8(*(const float4*)q, *(const float4*)(q + 4));
        }
    }

    float loss = 0.0f;
    int in_, im_, if_;
    {
        int s = blockIdx.x * SPB + wave * 32 + l31;
        in_ = pos_n[s]; im_ = pos_m[s]; if_ = pos_f[s];
    }

#pragma unroll 1
    for (int it = 0; it < iters; ++it) {
        const int in0 = in_, im0 = im_, if0 = if_;
        if (it + 1 < iters) {
            int s = ((it + 1) * NBLOCKS + blockIdx.x) * SPB + wave * 32 + l31;
            in_ = pos_n[s]; im_ = pos_m[s]; if_ = pos_f[s];
        }

#pragma unroll
        for (int i = 0; i < 8; ++i) {
            const int rl = i * 4 + srow;
            const int rn = __shfl(in0, rl, 64);
            float4 v = ((const float4*)(nci + (long)rn * 64))[schunk];
            *(uint2*)(nbase + rl * ROW_BYTES + schunk * 8) = pack4(v);
            const int rm = __shfl(im0, rl, 64);
            float4 w = ((const float4*)(nci + (long)rm * 64))[schunk];
            *(uint2*)(mbase + rl * ROW_BYTES + schunk * 8) = pack4(w);
        }
        asm volatile("" ::: "memory");

        floatx16 aN0{}, aN1{}, aM0{}, aM1{};
#pragma unroll
        for (int t = 0; t < 4; ++t) {
            half8 aF = *(const half8*)(nbase + l31 * ROW_BYTES + t * 32 + hi * 16);
            aN0 = __builtin_amdgcn_mfma_f32_32x32x16_f16(aF, Bn[0][t], aN0, 0, 0, 0);
            aN1 = __builtin_amdgcn_mfma_f32_32x32x16_f16(aF, Bn[1][t], aN1, 0, 0, 0);
            half8 bF = *(const half8*)(mbase + l31 * ROW_BYTES + t * 32 + hi * 16);
            aM0 = __builtin_amdgcn_mfma_f32_32x32x16_f16(bF, Bm[0][t], aM0, 0, 0, 0);
            aM1 = __builtin_amdgcn_mfma_f32_32x32x16_f16(bF, Bm[1][t], aM1, 0, 0, 0);
        }

#pragma unroll
        for (int r = 0; r < 16; ++r) {
            const int mrow = (r & 3) + 8 * (r >> 2) + 4 * hi;
            const int fid  = __shfl(if0, mrow, 64);
            const float* pf = fma_emb + (long)fid * 64 + l31;
            const float f0 = pf[0];
            const float f1 = pf[32];
            float d;
            d = aN0[r] - f0; loss = fmaf(d, d, loss);
            d = aM0[r] - f0; loss = fmaf(d, d, loss);
            d = aN1[r] - f1; loss = fmaf(d, d, loss);
            d = aM1[r] - f1; loss = fmaf(d, d, loss);
        }
    }

#pragma unroll
    for (int o = 32; o > 0; o >>= 1) loss += __shfl_xor(loss, o, 64);
    if (lane == 0) atomicAdd(out, loss);
}

extern "C" void kernel_launch(void* const* d_in, const int* in_sizes, int n_in,
                              void* d_out, int out_size, void* d_ws, size_t ws_size,
                              hipStream_t stream) {
    const int*   pos_n   = (const int*)d_in[0];
    const int*   pos_m   = (const int*)d_in[1];
    const int*   pos_f   = (const int*)d_in[2];
    const float* nci_emb = (const float*)d_in[3];
    const float* fma_emb = (const float*)d_in[4];
    const float* n2f_mat = (const float*)d_in[5];
    const float* m2f_mat = (const float*)d_in[6];
    float* out = (float*)d_out;

    const int B = in_sizes[0];
    const int iters = B / (NBLOCKS * SPB);  // 1,048,576 -> 8

    (void)hipMemsetAsync(out, 0, sizeof(float), stream);

    const size_t need = (size_t)NCI_ELEMS + (size_t)FMA_ELEMS;  // 16 MB
    if (ws_size >= need) {
        unsigned char* nci8 = (unsigned char*)d_ws;
        unsigned char* fma8 = nci8 + NCI_ELEMS;   // 9,600,000 is 64B-aligned
        convert_kernel<<<2048, 256, 0, stream>>>(
            (const float4*)nci_emb, (const float4*)fma_emb,
            (uint2*)nci8, (uint2*)fma8);
        ontomap_kernel_q<<<NBLOCKS, 256, 0, stream>>>(
            pos_n, pos_m, pos_f, nci8, fma8, n2f_mat, m2f_mat, out, iters);
    } else {
        ontomap_kernel_f32<<<NBLOCKS, 256, 0, stream>>>(
            pos_n, pos_m, pos_f, nci_emb, fma_emb, n2f_mat, m2f_mat, out, iters);
    }
}